// Round 6
// baseline (181.580 us; speedup 1.0000x reference)
//
#include <hip/hip_runtime.h>
#include <stdint.h>

// EdgeNetwork, round 6: algebraic restructure.
//   out[a] = K-contraction of S_a, where S_a = sum_{e:dst=a} bond_e (x) neigh_e
//   (push segment_sum inside the einsum: 5.6 GFLOP -> 0.5 GFLOP, all f32).
// K1: bin edge ids per dst (640K int atomics, 64B-strided counters).
// K2: one wave per atom: rank-1 accumulate S (4 VGPR/lane), then 68-step
//     dot with K^T from LDS. No MFMA, no message array (ws ~12 MB).
// History: r1 630us atomic scatter -> r2 CSR 333 -> r3 MFMA msg 190 ->
// r4/r5 binned MFMA 150/146 (msg latency-bound at 66us, ~1 instr/175cyc).

constexpr int DIM  = 16;
constexpr int CAP  = 64;     // slots per atom; P(deg>64) ~ 1e-8 at Poisson(32)
constexpr int CSTR = 16;     // counts stride (ints): one 64B line per atom
constexpr int OFLOW_CAP = 65536;

// ---- K1: per-edge binning (rank via padded atomic counters)
__global__ __launch_bounds__(256) void bin_kernel(
    const int* __restrict__ pair, int* __restrict__ counts,
    int* __restrict__ oflow_cnt, int* __restrict__ oflow,
    int2* __restrict__ bins, int n_edges)
{
    int e = blockIdx.x * blockDim.x + threadIdx.x;
    if (e >= n_edges) return;
    int2 pr = ((const int2*)pair)[e];               // x=dst, y=src (coalesced 8B)
    int r = atomicAdd(&counts[pr.x * CSTR], 1);
    if (r < CAP) {
        bins[pr.x * CAP + r] = make_int2(e, pr.y);  // one 8B scattered store
    } else {
        int oi = atomicAdd(oflow_cnt, 1);
        if (oi < OFLOW_CAP) oflow[oi] = e;
    }
}

// ---- K2: one wave per atom. S[k][j] distributed: lane(k=l>>2, j4=(l&3)*4)
// holds S[k][j4..j4+3]; lanes 0..3 also hold ns[j4..+3]. Then out[i] =
// sum_o Kt[o][i]*S_flat[o] over o=0..271 (row 256+ = bias/nsum).
__global__ __launch_bounds__(256) void atom_kernel(
    const float* __restrict__ atom, const float* __restrict__ bond,
    const float* __restrict__ kern, const float* __restrict__ bias,
    const int* __restrict__ counts, const int2* __restrict__ bins,
    float* __restrict__ out, int n_atoms)
{
    __shared__ float Kt[272 * 16];    // Kt[o*16+i]; o=(k*16+j) or 256+j. 17408 B
    __shared__ float Sl[4][272];      // per-wave S(256) + nsum(16). 4352 B

    const int tid  = threadIdx.x;
    const int lane = tid & 63;
    const int w    = tid >> 6;

    // stage K^T (+bias) once per block: Kt[(k*16+j)*16+i] = kern[k*256+i*16+j]
    for (int t = tid; t < 4096; t += 256) {
        float v = kern[t];
        int k = t >> 8, rem = t & 255, i = rem >> 4, j = rem & 15;
        Kt[(k * 16 + j) * 16 + i] = v;
    }
    if (tid < 256) {
        float v = bias[tid];
        int i = tid >> 4, j = tid & 15;
        Kt[(256 + j) * 16 + i] = v;
    }
    __syncthreads();

    const int  a      = blockIdx.x * 4 + w;
    const bool active = (a < n_atoms);

    const int k4 = lane >> 2;          // S row (bond feature)
    const int j4 = (lane & 3) * 4;     // S col quarter (neigh feature)

    if (active) {
        const int deg = min(counts[a * CSTR], CAP);

        // lane l caches bin entry l in registers; broadcast via shfl
        int be = 0, bs = 0;
        if (lane < deg) {
            int2 b = bins[a * CAP + lane];
            be = b.x; bs = b.y;
        }

        float4 S4  = {0.f, 0.f, 0.f, 0.f};
        float4 ns4 = {0.f, 0.f, 0.f, 0.f};
#pragma unroll 4
        for (int t = 0; t < deg; ++t) {
            const int e   = __shfl(be, t, 64);
            const int src = __shfl(bs, t, 64);
            // per step: exactly 2 cache-line requests (lane-deduplicated)
            const float  bv = bond[(size_t)e * DIM + k4];                  // 1 line
            const float4 nv = *(const float4*)(atom + (size_t)src * DIM + j4); // 1 line
            S4.x = fmaf(bv, nv.x, S4.x);
            S4.y = fmaf(bv, nv.y, S4.y);
            S4.z = fmaf(bv, nv.z, S4.z);
            S4.w = fmaf(bv, nv.w, S4.w);
            if (lane < 4) {            // nsum on 4 lanes (exec-masked, cheap)
                ns4.x += nv.x; ns4.y += nv.y; ns4.z += nv.z; ns4.w += nv.w;
            }
        }
        *(float4*)&Sl[w][k4 * 16 + j4] = S4;
        if (lane < 4) *(float4*)&Sl[w][256 + j4] = ns4;
    }
    __syncthreads();   // uniform: every thread reaches this

    if (active) {
        const int i = lane & 15, p = lane >> 4;
        float acc = 0.f;
#pragma unroll 4
        for (int q = 0; q < 68; ++q) {
            const int o = p + q * 4;                  // covers 0..271
            // Kt read: 2-way bank alias (free, m136); Sl read: 16-way broadcast
            acc = fmaf(Kt[o * 16 + i], Sl[w][o], acc);
        }
        acc += __shfl_xor(acc, 16, 64);
        acc += __shfl_xor(acc, 32, 64);
        if (lane < 16) out[(size_t)a * DIM + i] = acc;   // 64B coalesced
    }
}

// ---- overflow fix-up (normally 0 edges): exact f32 per-edge + atomicAdd
__global__ __launch_bounds__(256) void oflow_kernel(
    const float* __restrict__ atom, const float* __restrict__ bond,
    const int*   __restrict__ pair, const float* __restrict__ kern,
    const float* __restrict__ bias,
    const int* __restrict__ oflow_cnt, const int* __restrict__ oflow,
    float* __restrict__ out, int n_edges)
{
    int n = min(*oflow_cnt, OFLOW_CAP);
    for (int idx = blockIdx.x * blockDim.x + threadIdx.x; idx < n;
         idx += gridDim.x * blockDim.x) {
        int e   = oflow[idx];
        int dst = pair[2 * e + 0];
        int src = pair[2 * e + 1];
        float neigh[DIM], bnd[DIM], acc[DIM];
        for (int q = 0; q < DIM; ++q) neigh[q] = atom[(size_t)src * DIM + q];
        for (int q = 0; q < DIM; ++q) bnd[q]   = bond[(size_t)e * DIM + q];
#pragma unroll
        for (int ii = 0; ii < DIM; ++ii) {
            float d = 0.f;
#pragma unroll
            for (int j = 0; j < DIM; ++j) d = fmaf(bias[ii * DIM + j], neigh[j], d);
            acc[ii] = d;
        }
#pragma unroll 1
        for (int k = 0; k < DIM; ++k) {
            const float bk = bnd[k];
            const float* Kr = kern + k * (DIM * DIM);
#pragma unroll
            for (int ii = 0; ii < DIM; ++ii) {
                float d = 0.f;
#pragma unroll
                for (int j = 0; j < DIM; ++j) d = fmaf(Kr[ii * DIM + j], neigh[j], d);
                acc[ii] = fmaf(bk, d, acc[ii]);
            }
        }
#pragma unroll
        for (int ii = 0; ii < DIM; ++ii)
            atomicAdd(&out[(size_t)dst * DIM + ii], acc[ii]);
    }
}

// ---- safety fallback if ws too small (round-1 structure)
__global__ __launch_bounds__(256) void edge_atomic_kernel(
    const float* __restrict__ atom, const float* __restrict__ bond,
    const int*   __restrict__ pair, const float* __restrict__ kern,
    const float* __restrict__ bias, float* __restrict__ out, int n_edges)
{
    int e = blockIdx.x * blockDim.x + threadIdx.x;
    if (e >= n_edges) return;
    int dst = pair[2 * e + 0];
    int src = pair[2 * e + 1];
    float neigh[DIM], bnd[DIM], acc[DIM];
    for (int q = 0; q < DIM; ++q) neigh[q] = atom[(size_t)src * DIM + q];
    for (int q = 0; q < DIM; ++q) bnd[q]   = bond[(size_t)e * DIM + q];
#pragma unroll
    for (int i = 0; i < DIM; ++i) {
        float d = 0.f;
#pragma unroll
        for (int j = 0; j < DIM; ++j) d = fmaf(bias[i * DIM + j], neigh[j], d);
        acc[i] = d;
    }
#pragma unroll 1
    for (int k = 0; k < DIM; ++k) {
        const float bk = bnd[k];
        const float* Kr = kern + k * (DIM * DIM);
#pragma unroll
        for (int i = 0; i < DIM; ++i) {
            float d = 0.f;
#pragma unroll
            for (int j = 0; j < DIM; ++j) d = fmaf(Kr[i * DIM + j], neigh[j], d);
            acc[i] = fmaf(bk, d, acc[i]);
        }
    }
#pragma unroll
    for (int i = 0; i < DIM; ++i) atomicAdd(&out[(size_t)dst * DIM + i], acc[i]);
}

extern "C" void kernel_launch(void* const* d_in, const int* in_sizes, int n_in,
                              void* d_out, int out_size, void* d_ws, size_t ws_size,
                              hipStream_t stream)
{
    const float* atom = (const float*)d_in[0];   // (20000,16) f32
    const float* bond = (const float*)d_in[1];   // (640000,16) f32
    const int*   pair = (const int*)d_in[2];     // (640000,2) i32 [dst, src]
    const float* kern = (const float*)d_in[3];   // (16,256) f32
    const float* bias = (const float*)d_in[4];   // (256,) f32
    float*       out  = (float*)d_out;           // (20000,16) f32

    const int n_edges = in_sizes[1] / DIM;       // 640000
    const int n_atoms = in_sizes[0] / DIM;       // 20000

    // ws: counts[n_atoms*CSTR] | oflow_cnt | oflow[OFLOW_CAP] | 8B | bins int2
    size_t counts_off = 0;
    size_t ocnt_off   = counts_off + (size_t)n_atoms * CSTR * sizeof(int);
    size_t oflow_off  = ocnt_off + sizeof(int);
    size_t bins_off   = (oflow_off + (size_t)OFLOW_CAP * sizeof(int) + 7) & ~(size_t)7;
    size_t needed     = bins_off + (size_t)n_atoms * CAP * sizeof(int2);

    const int threads = 256;

    if (ws_size >= needed) {
        int*  counts    = (int*)((char*)d_ws + counts_off);
        int*  oflow_cnt = (int*)((char*)d_ws + ocnt_off);
        int*  oflow     = (int*)((char*)d_ws + oflow_off);
        int2* bins      = (int2*)((char*)d_ws + bins_off);

        // zero padded counts + adjacent oflow counter in one memset
        hipMemsetAsync(counts, 0,
                       (size_t)n_atoms * CSTR * sizeof(int) + sizeof(int), stream);

        bin_kernel<<<(n_edges + threads - 1) / threads, threads, 0, stream>>>(
            pair, counts, oflow_cnt, oflow, bins, n_edges);

        atom_kernel<<<(n_atoms + 3) / 4, threads, 0, stream>>>(
            atom, bond, kern, bias, counts, bins, out, n_atoms);

        oflow_kernel<<<8, threads, 0, stream>>>(
            atom, bond, pair, kern, bias, oflow_cnt, oflow, out, n_edges);
    } else {
        hipMemsetAsync(out, 0, (size_t)out_size * sizeof(float), stream);
        edge_atomic_kernel<<<(n_edges + threads - 1) / threads, threads, 0, stream>>>(
            atom, bond, pair, kern, bias, out, n_edges);
    }
}